// Round 2
// baseline (163.468 us; speedup 1.0000x reference)
//
#include <hip/hip_runtime.h>
#include <stdint.h>

#define T 49
#define CCH 256
#define NH 8
#define DH 32

typedef __bf16 bf16x8 __attribute__((ext_vector_type(8)));
typedef float f32x4 __attribute__((ext_vector_type(4)));

static __device__ __forceinline__ unsigned short f2bf(float f){
  uint32_t u = __builtin_bit_cast(uint32_t, f);
  u = u + 0x7fffu + ((u >> 16) & 1u);
  return (unsigned short)(u >> 16);
}
static __device__ __forceinline__ float bf2f(unsigned short h){
  return __builtin_bit_cast(float, ((uint32_t)h) << 16);
}
static __device__ __forceinline__ f32x4 mfma16(bf16x8 a, bf16x8 b, f32x4 c){
  return __builtin_amdgcn_mfma_f32_16x16x32_bf16(a, b, c, 0, 0, 0);
}
// XOR-swizzle of 16B chunks within 128B, keyed by low 3 bits of the row index.
#define SWZ(row) ((((row) & 7) << 4))

// ---------------- prep kernels ----------------

// wqkvT[p*256+n][k] = w_p[k][n] * (p==0 ? 1/sqrt(32) : 1), bf16
__global__ void prep_wqkvT(const float* __restrict__ wq, const float* __restrict__ wk,
                           const float* __restrict__ wv, unsigned short* __restrict__ out){
  int bk = blockIdx.x;            // 0..767
  int p = bk >> 8, kk = bk & 255;
  int n = threadIdx.x;
  const float* w = (p == 0) ? wq : (p == 1 ? wk : wv);
  float scl = (p == 0) ? 0.17677669529663687f : 1.0f;
  out[(size_t)(p * 256 + n) * 256 + kk] = f2bf(w[kk * 256 + n] * scl);
}

// wodT[c][hd] = sum_c' wo[hd][c'] * dw[c'][c], bf16
__global__ void prep_wodT(const float* __restrict__ wo, const float* __restrict__ dw,
                          unsigned short* __restrict__ out){
  int hd = blockIdx.x;            // 0..255
  int c = threadIdx.x;            // 0..255
  float s = 0.f;
  for (int cp = 0; cp < 256; ++cp) s = fmaf(wo[hd * 256 + cp], dw[cp * 256 + c], s);
  out[(size_t)c * 256 + hd] = f2bf(s);
}

// block 0: bqkv (q-scaled) + bod;  blocks 1..8: biasT[h][j][i] (transposed, pre-masked)
__global__ void prep_misc(const int* __restrict__ rp, const float* __restrict__ btab,
                          const float* __restrict__ bq, const float* __restrict__ bk,
                          const float* __restrict__ bv, const float* __restrict__ bo,
                          const float* __restrict__ dwm, const float* __restrict__ db,
                          unsigned short* __restrict__ biasT, float* __restrict__ bqkv,
                          float* __restrict__ bod){
  int t = threadIdx.x;
  if (blockIdx.x == 0){
    for (int idx = t; idx < 768; idx += 256){
      int p = idx >> 8, n = idx & 255;
      float v = (p == 0) ? bq[n] * 0.17677669529663687f : (p == 1 ? bk[n] : bv[n]);
      bqkv[idx] = v;
    }
    float s = db[t];
    for (int cp = 0; cp < 256; ++cp) s = fmaf(bo[cp], dwm[cp * 256 + t], s);
    bod[t] = s;
  } else {
    int h = blockIdx.x - 1;
    for (int idx = t; idx < 4096; idx += 256){
      int j = idx >> 6, i = idx & 63;
      float v;
      if (j >= T) v = -1e30f;            // mask pad K-tokens (finite, avoids inf-inf)
      else if (i >= T) v = 0.f;          // pad Q rows: anything finite
      else {
        int r0 = rp[i * 49 + j];
        int r1 = rp[2401 + i * 49 + j];
        v = btab[h * 169 + r0 * 13 + r1];
      }
      biasT[(size_t)(h * 64 + j) * 64 + i] = f2bf(v);
    }
  }
}

// ---------------- fused main kernel ----------------
// 1 block = 1 window; wave w = head w.
// LDS: xs [64][256] bf16 swizzled (reused for 'out'); q,k [8][64][40] bf16; vT [8][32][64] bf16 swizzled.
__launch_bounds__(512, 2)
__global__ void wmsa_main(const float* __restrict__ x,
                          const unsigned short* __restrict__ wqkvT,
                          const unsigned short* __restrict__ wodT,
                          const unsigned short* __restrict__ biasT,
                          const float* __restrict__ bqkv,
                          const float* __restrict__ bod,
                          float* __restrict__ y){
  __shared__ unsigned short xs[64 * 256];      // 32 KB
  __shared__ unsigned short qs[8 * 64 * 40];   // 40 KB
  __shared__ unsigned short ksh[8 * 64 * 40];  // 40 KB
  __shared__ unsigned short vts[8 * 32 * 64];  // 32 KB

  const int b    = blockIdx.x;
  const int tid  = threadIdx.x;
  const int h    = tid >> 6;       // wave == head
  const int lane = tid & 63;
  const int g    = lane >> 4;
  const int lo   = lane & 15;
  char* xs_c = (char*)xs;

  // ---- stage x -> xs (fp32->bf16, zero pad rows >= 49, swizzled) ----
  const float* xb = x + (size_t)b * T * CCH;
  for (int idx = tid; idx < 64 * 64; idx += 512){
    int row = idx >> 6, c4 = idx & 63;
    float4 v = make_float4(0.f, 0.f, 0.f, 0.f);
    if (row < T) v = reinterpret_cast<const float4*>(xb)[row * 64 + c4];
    uint32_t w0 = (uint32_t)f2bf(v.x) | ((uint32_t)f2bf(v.y) << 16);
    uint32_t w1 = (uint32_t)f2bf(v.z) | ((uint32_t)f2bf(v.w) << 16);
    *reinterpret_cast<uint2*>(xs_c + row * 512 + ((c4 * 8) ^ SWZ(row))) = make_uint2(w0, w1);
  }
  __syncthreads();

  // ---- QKV: wave h computes q,k,v channels of head h (6 n-tiles), M=64, K=256 ----
  f32x4 acc[4][6];
  #pragma unroll
  for (int mt = 0; mt < 4; ++mt)
    #pragma unroll
    for (int s = 0; s < 6; ++s) acc[mt][s] = f32x4{0.f, 0.f, 0.f, 0.f};

  for (int kt = 0; kt < 8; ++kt){
    bf16x8 a[4];
    #pragma unroll
    for (int mt = 0; mt < 4; ++mt){
      int row = 16 * mt + lo;
      a[mt] = *reinterpret_cast<const bf16x8*>(xs_c + row * 512 + ((kt * 64 + 16 * g) ^ SWZ(row)));
    }
    #pragma unroll
    for (int s = 0; s < 6; ++s){
      int p = s >> 1, nt = s & 1;
      int nrow = p * 256 + h * 32 + nt * 16 + lo;
      bf16x8 bfr = *reinterpret_cast<const bf16x8*>(wqkvT + (size_t)nrow * 256 + kt * 32 + 8 * g);
      #pragma unroll
      for (int mt = 0; mt < 4; ++mt) acc[mt][s] = mfma16(a[mt], bfr, acc[mt][s]);
    }
  }
  // epilogue: +bias, store q,k as [t][d] (stride 40), v transposed+swizzled [d][t]
  #pragma unroll
  for (int s = 0; s < 6; ++s){
    int p = s >> 1, nt = s & 1;
    int d = nt * 16 + lo;
    float bias = bqkv[p * 256 + h * 32 + d];
    #pragma unroll
    for (int mt = 0; mt < 4; ++mt){
      f32x4 t = acc[mt][s];
      if (p < 2){
        unsigned short* dst = (p == 0 ? qs : ksh) + h * 2560;
        #pragma unroll
        for (int r = 0; r < 4; ++r)
          dst[(16 * mt + 4 * g + r) * 40 + d] = f2bf(t[0 + r] + bias);
      } else {
        uint32_t w0 = (uint32_t)f2bf(t[0] + bias) | ((uint32_t)f2bf(t[1] + bias) << 16);
        uint32_t w1 = (uint32_t)f2bf(t[2] + bias) | ((uint32_t)f2bf(t[3] + bias) << 16);
        *reinterpret_cast<uint2*>((char*)vts + h * 4096 + d * 128 + ((mt * 32 + g * 8) ^ SWZ(d)))
            = make_uint2(w0, w1);
      }
    }
  }
  __syncthreads();   // all xs reads done; attention may overwrite xs with 'out'

  // ---- attention, swapped QK^T: L^T[j][i] = sum_d k[j][d] q[i][d] ----
  const char* qb = (const char*)qs + h * 5120;
  const char* kb = (const char*)ksh + h * 5120;
  bf16x8 ak[4], bq_[4];
  #pragma unroll
  for (int tt = 0; tt < 4; ++tt){
    int row = 16 * tt + lo;
    ak[tt]  = *reinterpret_cast<const bf16x8*>(kb + row * 80 + 16 * g);
    bq_[tt] = *reinterpret_cast<const bf16x8*>(qb + row * 80 + 16 * g);
  }
  f32x4 lacc[4][4];
  #pragma unroll
  for (int mt = 0; mt < 4; ++mt)
    #pragma unroll
    for (int nt = 0; nt < 4; ++nt)
      lacc[mt][nt] = mfma16(ak[mt], bq_[nt], f32x4{0.f, 0.f, 0.f, 0.f});

  // + bias (pre-masked, transposed)
  #pragma unroll
  for (int mt = 0; mt < 4; ++mt)
    #pragma unroll
    for (int nt = 0; nt < 4; ++nt)
      #pragma unroll
      for (int r = 0; r < 4; ++r){
        int j = 16 * mt + 4 * g + r, i = 16 * nt + lo;
        lacc[mt][nt][r] += bf2f(biasT[(size_t)(h * 64 + j) * 64 + i]);
      }

  // softmax over j (column i): in-lane over mt,r; cross-group via shfl_xor 16,32
  float rs[4];
  uint32_t pw[4][4][2];
  #pragma unroll
  for (int nt = 0; nt < 4; ++nt){
    float m = -3.0e38f;
    #pragma unroll
    for (int mt = 0; mt < 4; ++mt)
      #pragma unroll
      for (int r = 0; r < 4; ++r) m = fmaxf(m, lacc[mt][nt][r]);
    m = fmaxf(m, __shfl_xor(m, 16, 64));
    m = fmaxf(m, __shfl_xor(m, 32, 64));
    float ssum = 0.f;
    #pragma unroll
    for (int mt = 0; mt < 4; ++mt)
      #pragma unroll
      for (int r = 0; r < 4; ++r){
        float pv = exp2f((lacc[mt][nt][r] - m) * 1.4426950408889634f);
        lacc[mt][nt][r] = pv;
        ssum += pv;
      }
    ssum += __shfl_xor(ssum, 16, 64);
    ssum += __shfl_xor(ssum, 32, 64);
    rs[nt] = 1.f / ssum;
    #pragma unroll
    for (int mt = 0; mt < 4; ++mt){
      pw[mt][nt][0] = (uint32_t)f2bf(lacc[mt][nt][0]) | ((uint32_t)f2bf(lacc[mt][nt][1]) << 16);
      pw[mt][nt][1] = (uint32_t)f2bf(lacc[mt][nt][2]) | ((uint32_t)f2bf(lacc[mt][nt][3]) << 16);
    }
  }

  // ---- PV: out^T[d][i] = sum_j vT[d][j] * P^T[j][i]; P b-frags built via shuffles ----
  const char* vb = (const char*)vts + h * 4096;
  f32x4 oacc[2][4];
  #pragma unroll
  for (int mt = 0; mt < 2; ++mt)
    #pragma unroll
    for (int nt = 0; nt < 4; ++nt) oacc[mt][nt] = f32x4{0.f, 0.f, 0.f, 0.f};

  const int src_lo = lo + 32 * (g & 1);
  const int src_hi = src_lo + 16;
  #pragma unroll
  for (int kt = 0; kt < 2; ++kt){
    bf16x8 av[2];
    #pragma unroll
    for (int mt = 0; mt < 2; ++mt){
      int row = 16 * mt + lo;   // d
      av[mt] = *reinterpret_cast<const bf16x8*>(vb + row * 128 + ((kt * 64 + 16 * g) ^ SWZ(row)));
    }
    #pragma unroll
    for (int nt = 0; nt < 4; ++nt){
      uint32_t a0 = (uint32_t)__shfl((int)pw[2 * kt][nt][0], src_lo, 64);
      uint32_t a1 = (uint32_t)__shfl((int)pw[2 * kt][nt][1], src_lo, 64);
      uint32_t a2 = (uint32_t)__shfl((int)pw[2 * kt][nt][0], src_hi, 64);
      uint32_t a3 = (uint32_t)__shfl((int)pw[2 * kt][nt][1], src_hi, 64);
      uint32_t b0 = (uint32_t)__shfl((int)pw[2 * kt + 1][nt][0], src_lo, 64);
      uint32_t b1 = (uint32_t)__shfl((int)pw[2 * kt + 1][nt][1], src_lo, 64);
      uint32_t b2 = (uint32_t)__shfl((int)pw[2 * kt + 1][nt][0], src_hi, 64);
      uint32_t b3 = (uint32_t)__shfl((int)pw[2 * kt + 1][nt][1], src_hi, 64);
      uint4 fu = (g < 2) ? make_uint4(a0, a1, a2, a3) : make_uint4(b0, b1, b2, b3);
      bf16x8 pf = __builtin_bit_cast(bf16x8, fu);
      #pragma unroll
      for (int mt = 0; mt < 2; ++mt) oacc[mt][nt] = mfma16(av[mt], pf, oacc[mt][nt]);
    }
  }
  // normalize by 1/sum (per column i) and write out^T into xs as out[i][hd] (swizzled)
  #pragma unroll
  for (int nt = 0; nt < 4; ++nt){
    int i = 16 * nt + lo;
    float r0 = rs[nt];
    #pragma unroll
    for (int mt = 0; mt < 2; ++mt){
      f32x4 t = oacc[mt][nt];
      uint32_t w0 = (uint32_t)f2bf(t[0] * r0) | ((uint32_t)f2bf(t[1] * r0) << 16);
      uint32_t w1 = (uint32_t)f2bf(t[2] * r0) | ((uint32_t)f2bf(t[3] * r0) << 16);
      *reinterpret_cast<uint2*>(xs_c + i * 512 + ((h * 64 + mt * 32 + g * 8) ^ SWZ(i)))
          = make_uint2(w0, w1);
    }
  }
  __syncthreads();

  // ---- final GEMM: y[i][c] = sum_hd out[i][hd] * wodT[c][hd] + bod[c] ----
  f32x4 facc[4][2];
  #pragma unroll
  for (int mt = 0; mt < 4; ++mt)
    #pragma unroll
    for (int nt = 0; nt < 2; ++nt) facc[mt][nt] = f32x4{0.f, 0.f, 0.f, 0.f};

  for (int kt = 0; kt < 8; ++kt){
    bf16x8 a[4];
    #pragma unroll
    for (int mt = 0; mt < 4; ++mt){
      int row = 16 * mt + lo;
      a[mt] = *reinterpret_cast<const bf16x8*>(xs_c + row * 512 + ((kt * 64 + 16 * g) ^ SWZ(row)));
    }
    #pragma unroll
    for (int nt = 0; nt < 2; ++nt){
      int crow = h * 32 + nt * 16 + lo;
      bf16x8 bfr = *reinterpret_cast<const bf16x8*>(wodT + (size_t)crow * 256 + kt * 32 + 8 * g);
      #pragma unroll
      for (int mt = 0; mt < 4; ++mt) facc[mt][nt] = mfma16(a[mt], bfr, facc[mt][nt]);
    }
  }
  #pragma unroll
  for (int nt = 0; nt < 2; ++nt){
    int c = h * 32 + nt * 16 + lo;
    float bd = bod[c];
    #pragma unroll
    for (int mt = 0; mt < 4; ++mt)
      #pragma unroll
      for (int r = 0; r < 4; ++r){
        int i = 16 * mt + 4 * g + r;
        if (i < T) y[((size_t)b * T + i) * CCH + c] = facc[mt][nt][r] + bd;
      }
  }
}

// ---------------- launch ----------------
extern "C" void kernel_launch(void* const* d_in, const int* in_sizes, int n_in,
                              void* d_out, int out_size, void* d_ws, size_t ws_size,
                              hipStream_t stream){
  const float* x    = (const float*)d_in[0];
  const int*   rp   = (const int*)d_in[1];
  const float* btab = (const float*)d_in[2];
  const float* wq   = (const float*)d_in[3];
  const float* bq   = (const float*)d_in[4];
  const float* wk   = (const float*)d_in[5];
  const float* bk   = (const float*)d_in[6];
  const float* wv   = (const float*)d_in[7];
  const float* bv   = (const float*)d_in[8];
  const float* wo   = (const float*)d_in[9];
  const float* bo   = (const float*)d_in[10];
  const float* dw   = (const float*)d_in[11];
  const float* db   = (const float*)d_in[12];
  float* y = (float*)d_out;

  char* ws = (char*)d_ws;
  unsigned short* wqkvT = (unsigned short*)(ws);            // 393216 B
  unsigned short* wodT  = (unsigned short*)(ws + 393216);   // 131072 B
  unsigned short* biasT = (unsigned short*)(ws + 524288);   // 65536 B
  float* bqkv           = (float*)(ws + 589824);            // 3072 B
  float* bod            = (float*)(ws + 592896);            // 1024 B

  prep_wqkvT<<<768, 256, 0, stream>>>(wq, wk, wv, wqkvT);
  prep_wodT<<<256, 256, 0, stream>>>(wo, dw, wodT);
  prep_misc<<<9, 256, 0, stream>>>(rp, btab, bq, bk, bv, bo, dw, db, biasT, bqkv, bod);
  wmsa_main<<<1024, 512, 0, stream>>>(x, wqkvT, wodT, biasT, bqkv, bod, y);
}